// Round 1
// 1098.901 us; speedup vs baseline: 1.0946x; 1.0946x over previous
//
#include <hip/hip_runtime.h>

#define NA_ 100000
#define NH_ 20000
#define E_  1000000
#define EL_ 200000
#define D_  128

typedef __attribute__((ext_vector_type(8))) short short8;
typedef __attribute__((ext_vector_type(4))) float f32x4;

__device__ __forceinline__ ushort f2bf(float f) {
  union { float f; uint u; } v; v.f = f;
  uint u = v.u;
  return (ushort)((u + 0x7FFFu + ((u >> 16) & 1u)) >> 16);
}
__device__ __forceinline__ uint pack2bf(float a, float b) {
  return (uint)f2bf(a) | ((uint)f2bf(b) << 16);
}

// ---------------- fused fp32->bf16 conversion + edge counting ----------------
// grid covers NA_*32 + NH_*32 threads (float4 per thread); first 2E threads also count.

__global__ __launch_bounds__(256) void cvt_count_k(const float* __restrict__ xa, ushort* __restrict__ da,
                                                   const float* __restrict__ xh, ushort* __restrict__ dh,
                                                   const int* __restrict__ d1, int* __restrict__ c1,
                                                   const int* __restrict__ d2, int* __restrict__ c2) {
  int i = blockIdx.x * 256 + threadIdx.x;
  if (i < E_) atomicAdd(&c1[d1[i]], 1);
  else if (i < 2 * E_) atomicAdd(&c2[d2[i - E_]], 1);
  const int na4 = NA_ * 32;
  if (i < na4) {
    float4 v = *(const float4*)(xa + (size_t)i * 4);
    ((uint2*)da)[i] = make_uint2(pack2bf(v.x, v.y), pack2bf(v.z, v.w));
  } else {
    int k = i - na4;
    if (k < NH_ * 32) {
      float4 v = *(const float4*)(xh + (size_t)k * 4);
      ((uint2*)dh)[k] = make_uint2(pack2bf(v.x, v.y), pack2bf(v.z, v.w));
    }
  }
}

// ---------------- scan (also re-seeds cur = off in the same pass) ----------------

__global__ __launch_bounds__(1024) void scan2_k(int* __restrict__ c1, int* __restrict__ o1, int n1,
                                                int* __restrict__ c2, int* __restrict__ o2, int n2) {
  int* c = blockIdx.x ? c2 : c1;   // counts in, cur out (aliased)
  int* o = blockIdx.x ? o2 : o1;
  int n  = blockIdx.x ? n2 : n1;
  __shared__ int sums[1024];
  int t = threadIdx.x;
  int per = (n + 1023) >> 10;
  int s0 = t * per;
  int s1 = s0 + per; if (s1 > n) s1 = n;
  int loc = 0;
  for (int i = s0; i < s1; i++) loc += c[i];
  sums[t] = loc;
  __syncthreads();
  for (int sh = 1; sh < 1024; sh <<= 1) {
    int v = (t >= sh) ? sums[t - sh] : 0;
    __syncthreads();
    sums[t] += v;
    __syncthreads();
  }
  int run = (t == 0) ? 0 : sums[t - 1];
  for (int i = s0; i < s1; i++) {
    int ci = c[i];
    o[i] = run;
    c[i] = run;   // cur init fused here
    run += ci;
  }
  if (t == 1023) o[n] = run;
}

__global__ void fill_edges_k(const int* __restrict__ s1, const int* __restrict__ d1,
                             int* __restrict__ cur1, int* __restrict__ out1,
                             const int* __restrict__ s2, const int* __restrict__ d2,
                             int* __restrict__ cur2, int* __restrict__ out2) {
  int i = blockIdx.x * 256 + threadIdx.x;
  if (i < E_) {
    int p = atomicAdd(&cur1[d1[i]], 1);
    out1[p] = s1[i];
  } else if (i < 2 * E_) {
    int ii = i - E_;
    int p = atomicAdd(&cur2[d2[ii]], 1);
    out2[p] = s2[ii];
  }
}

// ---------------- pack [Wl;Wr] (K=256, N=128) into MFMA B-frag layout, bf16 ----------------

__global__ void pack_all_k(const float* a0, const float* a1, ushort* ad,
                           const float* b0, const float* b1, ushort* bd,
                           const float* c0, const float* c1, ushort* cd,
                           const float* d0, const float* d1, ushort* dd,
                           const float* e0, const float* e1, ushort* ed) {
  const float *s0, *s1; ushort* dst;
  switch (blockIdx.y) {
    case 0: s0 = a0; s1 = a1; dst = ad; break;
    case 1: s0 = b0; s1 = b1; dst = bd; break;
    case 2: s0 = c0; s1 = c1; dst = cd; break;
    case 3: s0 = d0; s1 = d1; dst = dd; break;
    default: s0 = e0; s1 = e1; dst = ed; break;
  }
  int idx = blockIdx.x * 256 + threadIdx.x;  // 0..32767
  int j = idx & 7, lane = (idx >> 3) & 63, nt = (idx >> 9) & 7, kc = idx >> 12;
  int k = kc * 32 + (lane >> 4) * 8 + j;
  int n = nt * 16 + (lane & 15);
  float v = (k < 128) ? s0[k * 128 + n] : s1[(k - 128) * 128 + n];
  dst[idx] = f2bf(v);
}

// ---------------- mean aggregation: wave per dst row, 16 lanes per row slice ----------------
// 4 lane-groups process 4 edges per VMEM instruction (uint4 = 16B = 8 bf16 per lane),
// 2-wide unrolled -> 8 edges in flight; cross-group combine via shfl_xor(16/32).

__global__ __launch_bounds__(256) void aggregate_bf_k(const ushort* __restrict__ xsrc,
                                                      const int* __restrict__ off,
                                                      const int* __restrict__ srcs,
                                                      ushort* __restrict__ out, int ndst) {
  int w = (blockIdx.x * 256 + threadIdx.x) >> 6;
  int lane = threadIdx.x & 63;
  if (w >= ndst) return;
  const int grp = lane >> 4, sub = lane & 15;
  int beg = off[w], end = off[w + 1];
  float a[8] = {0.f, 0.f, 0.f, 0.f, 0.f, 0.f, 0.f, 0.f};
  const ushort* base = xsrc + sub * 8;
  int j = beg + grp;
  for (; j + 4 < end; j += 8) {
    int sA = srcs[j];
    int sB = srcs[j + 4];
    uint4 vA = *(const uint4*)(base + (size_t)sA * 128);
    uint4 vB = *(const uint4*)(base + (size_t)sB * 128);
    a[0] += __uint_as_float(vA.x << 16); a[1] += __uint_as_float(vA.x & 0xFFFF0000u);
    a[2] += __uint_as_float(vA.y << 16); a[3] += __uint_as_float(vA.y & 0xFFFF0000u);
    a[4] += __uint_as_float(vA.z << 16); a[5] += __uint_as_float(vA.z & 0xFFFF0000u);
    a[6] += __uint_as_float(vA.w << 16); a[7] += __uint_as_float(vA.w & 0xFFFF0000u);
    a[0] += __uint_as_float(vB.x << 16); a[1] += __uint_as_float(vB.x & 0xFFFF0000u);
    a[2] += __uint_as_float(vB.y << 16); a[3] += __uint_as_float(vB.y & 0xFFFF0000u);
    a[4] += __uint_as_float(vB.z << 16); a[5] += __uint_as_float(vB.z & 0xFFFF0000u);
    a[6] += __uint_as_float(vB.w << 16); a[7] += __uint_as_float(vB.w & 0xFFFF0000u);
  }
  if (j < end) {
    int sA = srcs[j];
    uint4 vA = *(const uint4*)(base + (size_t)sA * 128);
    a[0] += __uint_as_float(vA.x << 16); a[1] += __uint_as_float(vA.x & 0xFFFF0000u);
    a[2] += __uint_as_float(vA.y << 16); a[3] += __uint_as_float(vA.y & 0xFFFF0000u);
    a[4] += __uint_as_float(vA.z << 16); a[5] += __uint_as_float(vA.z & 0xFFFF0000u);
    a[6] += __uint_as_float(vA.w << 16); a[7] += __uint_as_float(vA.w & 0xFFFF0000u);
  }
#pragma unroll
  for (int k = 0; k < 8; k++) {
    a[k] += __shfl_xor(a[k], 16);
    a[k] += __shfl_xor(a[k], 32);
  }
  int deg = end - beg;
  float sc = 1.0f / (float)(deg > 0 ? deg : 1);
  if (grp == 0) {
    uint4 o;
    o.x = pack2bf(a[0] * sc, a[1] * sc);
    o.y = pack2bf(a[2] * sc, a[3] * sc);
    o.z = pack2bf(a[4] * sc, a[5] * sc);
    o.w = pack2bf(a[6] * sc, a[7] * sc);
    *(uint4*)(out + (size_t)w * 128 + sub * 8) = o;
  }
}

// ---------------- SAGE transform via MFMA: out = act([A|X] @ Wp + bias) ----------------

template <bool RELU, bool OUTBF>
__global__ __launch_bounds__(256) void sage_mfma_k(const ushort* __restrict__ Abf,
                                                   const ushort* __restrict__ Xbf,
                                                   const ushort* __restrict__ Wp,
                                                   const float* __restrict__ bias,
                                                   float* __restrict__ outF,
                                                   ushort* __restrict__ outB, int rows) {
  const int t = threadIdx.x;
  const int w = t >> 6, lane = t & 63, quad = lane >> 4, m = lane & 15;
  const int row0 = blockIdx.x * 64 + w * 16;
  int rA = row0 + m; if (rA >= rows) rA = rows - 1;
  f32x4 acc[8];
#pragma unroll
  for (int nt = 0; nt < 8; nt++) acc[nt] = (f32x4){0.f, 0.f, 0.f, 0.f};
#pragma unroll
  for (int kc = 0; kc < 8; kc++) {
    const ushort* src = (kc < 4) ? (Abf + (size_t)rA * 128 + kc * 32)
                                 : (Xbf + (size_t)rA * 128 + (kc - 4) * 32);
    short8 a = *(const short8*)(src + quad * 8);
    const ushort* wp = Wp + (size_t)(kc * 8) * 512 + lane * 8;
#pragma unroll
    for (int nt = 0; nt < 8; nt++) {
      short8 b = *(const short8*)(wp + nt * 512);
      acc[nt] = __builtin_amdgcn_mfma_f32_16x16x32_bf16(a, b, acc[nt], 0, 0, 0);
    }
  }
#pragma unroll
  for (int nt = 0; nt < 8; nt++) {
    float bv = bias[nt * 16 + m];
#pragma unroll
    for (int r = 0; r < 4; r++) {
      int row = row0 + quad * 4 + r;
      if (row < rows) {
        float v = acc[nt][r] + bv;
        if (RELU) v = fmaxf(v, 0.f);
        if (OUTBF) outB[(size_t)row * 128 + nt * 16 + m] = f2bf(v);
        else       outF[(size_t)row * 128 + nt * 16 + m] = v;
      }
    }
  }
}

// ---------------- decoder: gather z1 -> MFMA z2 -> pred (nontemporal output streams) -----

__global__ __launch_bounds__(256) void decoder_mfma_k(const float* __restrict__ Za,
                                                      const float* __restrict__ Zh,
                                                      const int* __restrict__ rowi,
                                                      const int* __restrict__ coli,
                                                      const ushort* __restrict__ Wp,
                                                      const float* __restrict__ b1,
                                                      const float* __restrict__ W2,
                                                      const float* __restrict__ b2,
                                                      float* __restrict__ pred,
                                                      float* __restrict__ z1o,
                                                      float* __restrict__ z2o) {
  __shared__ ushort z1bf[64 * 264];  // row stride 264 bf16 = 528 B
  __shared__ int ra[64], rc[64];
  const int t = threadIdx.x, w = t >> 6, lane = t & 63, quad = lane >> 4, m = lane & 15;
  const int rb = blockIdx.x * 64;
  if (t < 64) ra[t] = rowi[rb + t];
  else if (t < 128) rc[t - 64] = coli[rb + t - 64];
  __syncthreads();
#pragma unroll 4
  for (int rr = 0; rr < 16; rr++) {
    int row = w * 16 + rr;
    int a = ra[row], c = rc[row];
    float2 va = *(const float2*)(Za + (size_t)a * 128 + lane * 2);
    float2 vc = *(const float2*)(Zh + (size_t)c * 128 + lane * 2);
    float* zr = z1o + (size_t)(rb + row) * 256;
    __builtin_nontemporal_store(*(const double*)&va, (double*)(zr + lane * 2));
    __builtin_nontemporal_store(*(const double*)&vc, (double*)(zr + 128 + lane * 2));
    uint* lbase = (uint*)(z1bf + row * 264);
    lbase[lane] = pack2bf(va.x, va.y);
    lbase[64 + lane] = pack2bf(vc.x, vc.y);
  }
  __syncthreads();
  f32x4 acc[8];
#pragma unroll
  for (int nt = 0; nt < 8; nt++) acc[nt] = (f32x4){0.f, 0.f, 0.f, 0.f};
#pragma unroll
  for (int kc = 0; kc < 8; kc++) {
    short8 a = *(const short8*)(z1bf + (w * 16 + m) * 264 + kc * 32 + quad * 8);
    const ushort* wp = Wp + (size_t)(kc * 8) * 512 + lane * 8;
#pragma unroll
    for (int nt = 0; nt < 8; nt++) {
      short8 b = *(const short8*)(wp + nt * 512);
      acc[nt] = __builtin_amdgcn_mfma_f32_16x16x32_bf16(a, b, acc[nt], 0, 0, 0);
    }
  }
  float part[4] = {0.f, 0.f, 0.f, 0.f};
#pragma unroll
  for (int nt = 0; nt < 8; nt++) {
    float bv = b1[nt * 16 + m];
    float wv = W2[nt * 16 + m];
#pragma unroll
    for (int r = 0; r < 4; r++) {
      float v = fmaxf(acc[nt][r] + bv, 0.f);
      __builtin_nontemporal_store(v, z2o + (size_t)(rb + w * 16 + quad * 4 + r) * 128 + nt * 16 + m);
      part[r] += v * wv;
    }
  }
  const float bias2 = b2[0];
#pragma unroll
  for (int r = 0; r < 4; r++) {
    float s = part[r];
    s += __shfl_xor(s, 1); s += __shfl_xor(s, 2);
    s += __shfl_xor(s, 4); s += __shfl_xor(s, 8);
    if (m == 0) pred[rb + w * 16 + quad * 4 + r] = s + bias2;
  }
}

// ---------------- host ----------------

static inline char* carve(char*& p, size_t bytes) {
  char* r = p;
  p += (bytes + 255) & ~(size_t)255;
  return r;
}

extern "C" void kernel_launch(void* const* d_in, const int* in_sizes, int n_in,
                              void* d_out, int out_size, void* d_ws, size_t ws_size,
                              hipStream_t stream) {
  const float* x_author = (const float*)d_in[0];
  const float* x_hotel  = (const float*)d_in[1];
  const int* ei_ah_src  = (const int*)d_in[2];
  const int* ei_ah_dst  = (const int*)d_in[3];
  const int* ei_ha_src  = (const int*)d_in[4];
  const int* ei_ha_dst  = (const int*)d_in[5];
  const int* eli_row    = (const int*)d_in[6];
  const int* eli_col    = (const int*)d_in[7];
  const float* W1_ah_l  = (const float*)d_in[8];
  const float* W1_ah_r  = (const float*)d_in[9];
  const float* W1_ha_l  = (const float*)d_in[10];
  const float* W1_ha_r  = (const float*)d_in[11];
  const float* W2_ah_l  = (const float*)d_in[12];
  const float* W2_ah_r  = (const float*)d_in[13];
  const float* W2_ha_l  = (const float*)d_in[14];
  const float* W2_ha_r  = (const float*)d_in[15];
  const float* b1_ah_l  = (const float*)d_in[16];
  const float* b1_ha_l  = (const float*)d_in[17];
  const float* b2_ah_l  = (const float*)d_in[18];
  const float* b2_ha_l  = (const float*)d_in[19];
  const float* W_lin1   = (const float*)d_in[20];
  const float* b_lin1   = (const float*)d_in[21];
  const float* W_lin2   = (const float*)d_in[22];
  const float* b_lin2   = (const float*)d_in[23];

  char* p = (char*)d_ws;
  ushort* xa_bf = (ushort*)carve(p, (size_t)NA_ * D_ * 2);
  ushort* xh_bf = (ushort*)carve(p, (size_t)NH_ * D_ * 2);
  ushort* A_hbf = (ushort*)carve(p, (size_t)NH_ * D_ * 2);
  ushort* A_abf = (ushort*)carve(p, (size_t)NA_ * D_ * 2);
  ushort* H_hbf = (ushort*)carve(p, (size_t)NH_ * D_ * 2);
  ushort* H_abf = (ushort*)carve(p, (size_t)NA_ * D_ * 2);
  float*  Z_h   = (float*)carve(p, (size_t)NH_ * D_ * 4);
  float*  Z_a   = (float*)carve(p, (size_t)NA_ * D_ * 4);
  ushort* Wp1ah = (ushort*)carve(p, 32768 * 2);
  ushort* Wp1ha = (ushort*)carve(p, 32768 * 2);
  ushort* Wp2ah = (ushort*)carve(p, 32768 * 2);
  ushort* Wp2ha = (ushort*)carve(p, 32768 * 2);
  ushort* WpD   = (ushort*)carve(p, 32768 * 2);
  int* off_h = (int*)carve(p, (size_t)(NH_ + 1) * 4);
  int* off_a = (int*)carve(p, (size_t)(NA_ + 1) * 4);
  int* cur_h = (int*)carve(p, (size_t)(NH_ + NA_) * 4);
  int* cur_a = cur_h + NH_;
  int* s_ah  = (int*)carve(p, (size_t)E_ * 4);
  int* s_ha  = (int*)carve(p, (size_t)E_ * 4);

  float* pred = (float*)d_out;
  float* z1o  = pred + EL_;
  float* z2o  = z1o + (size_t)EL_ * 256;

  // --- counts + bf16 conversion (fused) ---
  hipMemsetAsync(cur_h, 0, (size_t)(NH_ + NA_) * 4, stream);
  cvt_count_k<<<(NA_ * 32 + NH_ * 32 + 255) / 256, 256, 0, stream>>>(
      x_author, xa_bf, x_hotel, xh_bf, ei_ah_dst, cur_h, ei_ha_dst, cur_a);
  scan2_k<<<2, 1024, 0, stream>>>(cur_h, off_h, NH_, cur_a, off_a, NA_);
  fill_edges_k<<<(2 * E_ + 255) / 256, 256, 0, stream>>>(ei_ah_src, ei_ah_dst, cur_h, s_ah,
                                                         ei_ha_src, ei_ha_dst, cur_a, s_ha);

  // --- weight packing ---
  dim3 pg(128, 5);
  pack_all_k<<<pg, 256, 0, stream>>>(W1_ah_l, W1_ah_r, Wp1ah,
                                     W1_ha_l, W1_ha_r, Wp1ha,
                                     W2_ah_l, W2_ah_r, Wp2ah,
                                     W2_ha_l, W2_ha_r, Wp2ha,
                                     W_lin1, W_lin1 + 128 * 128, WpD);

  // --- layer 1 ---
  aggregate_bf_k<<<(NH_ + 3) / 4, 256, 0, stream>>>(xa_bf, off_h, s_ah, A_hbf, NH_);
  sage_mfma_k<true, true><<<(NH_ + 63) / 64, 256, 0, stream>>>(A_hbf, xh_bf, Wp1ah, b1_ah_l, nullptr, H_hbf, NH_);
  aggregate_bf_k<<<(NA_ + 3) / 4, 256, 0, stream>>>(xh_bf, off_a, s_ha, A_abf, NA_);
  sage_mfma_k<true, true><<<(NA_ + 63) / 64, 256, 0, stream>>>(A_abf, xa_bf, Wp1ha, b1_ha_l, nullptr, H_abf, NA_);

  // --- layer 2 (fp32 outputs) ---
  aggregate_bf_k<<<(NH_ + 3) / 4, 256, 0, stream>>>(H_abf, off_h, s_ah, A_hbf, NH_);
  sage_mfma_k<false, false><<<(NH_ + 63) / 64, 256, 0, stream>>>(A_hbf, H_hbf, Wp2ah, b2_ah_l, Z_h, nullptr, NH_);
  aggregate_bf_k<<<(NA_ + 3) / 4, 256, 0, stream>>>(H_hbf, off_a, s_ha, A_abf, NA_);
  sage_mfma_k<false, false><<<(NA_ + 63) / 64, 256, 0, stream>>>(A_abf, H_abf, Wp2ha, b2_ha_l, Z_a, nullptr, NA_);

  // --- decoder ---
  decoder_mfma_k<<<EL_ / 64, 256, 0, stream>>>(Z_a, Z_h, eli_row, eli_col,
                                               WpD, b_lin1, W_lin2, b_lin2,
                                               pred, z1o, z2o);
}

// Round 2
// 904.892 us; speedup vs baseline: 1.3293x; 1.2144x over previous
//
#include <hip/hip_runtime.h>

#define NA_ 100000
#define NH_ 20000
#define E_  1000000
#define EL_ 200000
#define D_  128

// hierarchical scan geometry: 1024 elements per chunk
#define NBH_ 20    // ceil(NH/1024)
#define NBA_ 98    // ceil(NA/1024)
#define NBT_ 118   // NBH_ + NBA_

typedef __attribute__((ext_vector_type(8))) short short8;
typedef __attribute__((ext_vector_type(4))) float f32x4;

__device__ __forceinline__ ushort f2bf(float f) {
  union { float f; uint u; } v; v.f = f;
  uint u = v.u;
  return (ushort)((u + 0x7FFFu + ((u >> 16) & 1u)) >> 16);
}
__device__ __forceinline__ uint pack2bf(float a, float b) {
  return (uint)f2bf(a) | ((uint)f2bf(b) << 16);
}

// ---------------- fused fp32->bf16 conversion + edge counting ----------------

__global__ __launch_bounds__(256) void cvt_count_k(const float* __restrict__ xa, ushort* __restrict__ da,
                                                   const float* __restrict__ xh, ushort* __restrict__ dh,
                                                   const int* __restrict__ d1, int* __restrict__ c1,
                                                   const int* __restrict__ d2, int* __restrict__ c2) {
  int i = blockIdx.x * 256 + threadIdx.x;
  if (i < E_) atomicAdd(&c1[d1[i]], 1);
  else if (i < 2 * E_) atomicAdd(&c2[d2[i - E_]], 1);
  const int na4 = NA_ * 32;
  if (i < na4) {
    float4 v = *(const float4*)(xa + (size_t)i * 4);
    ((uint2*)da)[i] = make_uint2(pack2bf(v.x, v.y), pack2bf(v.z, v.w));
  } else {
    int k = i - na4;
    if (k < NH_ * 32) {
      float4 v = *(const float4*)(xh + (size_t)k * 4);
      ((uint2*)dh)[k] = make_uint2(pack2bf(v.x, v.y), pack2bf(v.z, v.w));
    }
  }
}

// ---------------- hierarchical CSR prefix scan ----------------
// phase 1: per-chunk sums (chunk = 1024 counts)

__global__ __launch_bounds__(256) void csr_partial_k(const int* __restrict__ cnt_h,
                                                     const int* __restrict__ cnt_a,
                                                     int* __restrict__ partials) {
  int b = blockIdx.x;
  bool isH = b < NBH_;
  const int* c = isH ? cnt_h : cnt_a;
  int n = isH ? NH_ : NA_;
  int chunk = isH ? b : b - NBH_;
  int t = threadIdx.x;
  int i0 = chunk * 1024 + t * 4;
  int s = 0;
  if (i0 + 3 < n) {
    int4 v = *(const int4*)(c + i0);
    s = v.x + v.y + v.z + v.w;
  } else {
    for (int k = 0; k < 4; k++) if (i0 + k < n) s += c[i0 + k];
  }
#pragma unroll
  for (int d = 1; d < 64; d <<= 1) s += __shfl_xor(s, d);
  __shared__ int ws[4];
  int lane = t & 63, wv = t >> 6;
  if (lane == 0) ws[wv] = s;
  __syncthreads();
  if (t == 0) partials[b] = ws[0] + ws[1] + ws[2] + ws[3];
}

// phase 2: segmented exclusive scan of the 118 chunk sums (1 block)

__global__ __launch_bounds__(128) void csr_scanp_k(int* __restrict__ partials,
                                                   int* __restrict__ off_h,
                                                   int* __restrict__ off_a) {
  __shared__ int s[128];
  int t = threadIdx.x;
  int orig = (t < NBT_) ? partials[t] : 0;
  int seg = (t < NBH_) ? 0 : 1;
  s[t] = orig;
  __syncthreads();
  for (int d = 1; d < 128; d <<= 1) {
    int v = 0;
    if (t >= d) {
      int o = t - d;
      if (((o < NBH_) ? 0 : 1) == seg) v = s[o];
    }
    __syncthreads();
    s[t] += v;
    __syncthreads();
  }
  if (t < NBT_) partials[t] = s[t] - orig;  // exclusive base per chunk
  if (t == 0) { off_h[NH_] = E_; off_a[NA_] = E_; }  // degree totals are exactly E
}

// phase 3: in-chunk exclusive scan + chunk base -> off & cur

__global__ __launch_bounds__(256) void csr_scatter_k(int* __restrict__ cnt_h, int* __restrict__ off_h,
                                                     int* __restrict__ cnt_a, int* __restrict__ off_a,
                                                     const int* __restrict__ partials) {
  int b = blockIdx.x;
  bool isH = b < NBH_;
  int* c = isH ? cnt_h : cnt_a;     // counts in, cur out (aliased buffer)
  int* off = isH ? off_h : off_a;
  int n = isH ? NH_ : NA_;
  int chunk = isH ? b : b - NBH_;
  int t = threadIdx.x, lane = t & 63, wv = t >> 6;
  int base = partials[b];
  int i0 = chunk * 1024 + t * 4;
  int v0 = 0, v1 = 0, v2 = 0, v3 = 0;
  if (i0 + 3 < n) {
    int4 v = *(const int4*)(c + i0);
    v0 = v.x; v1 = v.y; v2 = v.z; v3 = v.w;
  } else {
    if (i0 < n) v0 = c[i0];
    if (i0 + 1 < n) v1 = c[i0 + 1];
    if (i0 + 2 < n) v2 = c[i0 + 2];
    if (i0 + 3 < n) v3 = c[i0 + 3];
  }
  int tsum = v0 + v1 + v2 + v3;
  int x = tsum;
#pragma unroll
  for (int d = 1; d < 64; d <<= 1) { int y = __shfl_up(x, d); if (lane >= d) x += y; }
  __shared__ int ws[4], wb[4];
  if (lane == 63) ws[wv] = x;
  __syncthreads();
  if (t == 0) { int r = 0; for (int i = 0; i < 4; i++) { wb[i] = r; r += ws[i]; } }
  __syncthreads();
  int run = base + wb[wv] + (x - tsum);
  int o0 = run, o1 = o0 + v0, o2 = o1 + v1, o3 = o2 + v2;
  if (i0 + 3 < n) {
    *(int4*)(off + i0) = make_int4(o0, o1, o2, o3);
    *(int4*)(c + i0) = make_int4(o0, o1, o2, o3);
  } else {
    if (i0 < n) { off[i0] = o0; c[i0] = o0; }
    if (i0 + 1 < n) { off[i0 + 1] = o1; c[i0 + 1] = o1; }
    if (i0 + 2 < n) { off[i0 + 2] = o2; c[i0 + 2] = o2; }
    if (i0 + 3 < n) { off[i0 + 3] = o3; c[i0 + 3] = o3; }
  }
}

__global__ void fill_edges_k(const int* __restrict__ s1, const int* __restrict__ d1,
                             int* __restrict__ cur1, int* __restrict__ out1,
                             const int* __restrict__ s2, const int* __restrict__ d2,
                             int* __restrict__ cur2, int* __restrict__ out2) {
  int i = blockIdx.x * 256 + threadIdx.x;
  if (i < E_) {
    int p = atomicAdd(&cur1[d1[i]], 1);
    out1[p] = s1[i];
  } else if (i < 2 * E_) {
    int ii = i - E_;
    int p = atomicAdd(&cur2[d2[ii]], 1);
    out2[p] = s2[ii];
  }
}

// ---------------- pack [Wl;Wr] (K=256, N=128) into MFMA B-frag layout, bf16 ----------------

__global__ void pack_all_k(const float* a0, const float* a1, ushort* ad,
                           const float* b0, const float* b1, ushort* bd,
                           const float* c0, const float* c1, ushort* cd,
                           const float* d0, const float* d1, ushort* dd,
                           const float* e0, const float* e1, ushort* ed) {
  const float *s0, *s1; ushort* dst;
  switch (blockIdx.y) {
    case 0: s0 = a0; s1 = a1; dst = ad; break;
    case 1: s0 = b0; s1 = b1; dst = bd; break;
    case 2: s0 = c0; s1 = c1; dst = cd; break;
    case 3: s0 = d0; s1 = d1; dst = dd; break;
    default: s0 = e0; s1 = e1; dst = ed; break;
  }
  int idx = blockIdx.x * 256 + threadIdx.x;  // 0..32767
  int j = idx & 7, lane = (idx >> 3) & 63, nt = (idx >> 9) & 7, kc = idx >> 12;
  int k = kc * 32 + (lane >> 4) * 8 + j;
  int n = nt * 16 + (lane & 15);
  float v = (k < 128) ? s0[k * 128 + n] : s1[(k - 128) * 128 + n];
  dst[idx] = f2bf(v);
}

// ---------------- mean aggregation: wave per dst row, 16 lanes per row slice ----------------

__global__ __launch_bounds__(256) void aggregate_bf_k(const ushort* __restrict__ xsrc,
                                                      const int* __restrict__ off,
                                                      const int* __restrict__ srcs,
                                                      ushort* __restrict__ out, int ndst) {
  int w = (blockIdx.x * 256 + threadIdx.x) >> 6;
  int lane = threadIdx.x & 63;
  if (w >= ndst) return;
  const int grp = lane >> 4, sub = lane & 15;
  int beg = off[w], end = off[w + 1];
  float a[8] = {0.f, 0.f, 0.f, 0.f, 0.f, 0.f, 0.f, 0.f};
  const ushort* base = xsrc + sub * 8;
  int j = beg + grp;
  for (; j + 4 < end; j += 8) {
    int sA = srcs[j];
    int sB = srcs[j + 4];
    uint4 vA = *(const uint4*)(base + (size_t)sA * 128);
    uint4 vB = *(const uint4*)(base + (size_t)sB * 128);
    a[0] += __uint_as_float(vA.x << 16); a[1] += __uint_as_float(vA.x & 0xFFFF0000u);
    a[2] += __uint_as_float(vA.y << 16); a[3] += __uint_as_float(vA.y & 0xFFFF0000u);
    a[4] += __uint_as_float(vA.z << 16); a[5] += __uint_as_float(vA.z & 0xFFFF0000u);
    a[6] += __uint_as_float(vA.w << 16); a[7] += __uint_as_float(vA.w & 0xFFFF0000u);
    a[0] += __uint_as_float(vB.x << 16); a[1] += __uint_as_float(vB.x & 0xFFFF0000u);
    a[2] += __uint_as_float(vB.y << 16); a[3] += __uint_as_float(vB.y & 0xFFFF0000u);
    a[4] += __uint_as_float(vB.z << 16); a[5] += __uint_as_float(vB.z & 0xFFFF0000u);
    a[6] += __uint_as_float(vB.w << 16); a[7] += __uint_as_float(vB.w & 0xFFFF0000u);
  }
  if (j < end) {
    int sA = srcs[j];
    uint4 vA = *(const uint4*)(base + (size_t)sA * 128);
    a[0] += __uint_as_float(vA.x << 16); a[1] += __uint_as_float(vA.x & 0xFFFF0000u);
    a[2] += __uint_as_float(vA.y << 16); a[3] += __uint_as_float(vA.y & 0xFFFF0000u);
    a[4] += __uint_as_float(vA.z << 16); a[5] += __uint_as_float(vA.z & 0xFFFF0000u);
    a[6] += __uint_as_float(vA.w << 16); a[7] += __uint_as_float(vA.w & 0xFFFF0000u);
  }
#pragma unroll
  for (int k = 0; k < 8; k++) {
    a[k] += __shfl_xor(a[k], 16);
    a[k] += __shfl_xor(a[k], 32);
  }
  int deg = end - beg;
  float sc = 1.0f / (float)(deg > 0 ? deg : 1);
  if (grp == 0) {
    uint4 o;
    o.x = pack2bf(a[0] * sc, a[1] * sc);
    o.y = pack2bf(a[2] * sc, a[3] * sc);
    o.z = pack2bf(a[4] * sc, a[5] * sc);
    o.w = pack2bf(a[6] * sc, a[7] * sc);
    *(uint4*)(out + (size_t)w * 128 + sub * 8) = o;
  }
}

// ---------------- SAGE transform via MFMA: out = act([A|X] @ Wp + bias) ----------------

template <bool RELU, bool OUTBF>
__global__ __launch_bounds__(256) void sage_mfma_k(const ushort* __restrict__ Abf,
                                                   const ushort* __restrict__ Xbf,
                                                   const ushort* __restrict__ Wp,
                                                   const float* __restrict__ bias,
                                                   float* __restrict__ outF,
                                                   ushort* __restrict__ outB, int rows) {
  const int t = threadIdx.x;
  const int w = t >> 6, lane = t & 63, quad = lane >> 4, m = lane & 15;
  const int row0 = blockIdx.x * 64 + w * 16;
  int rA = row0 + m; if (rA >= rows) rA = rows - 1;
  f32x4 acc[8];
#pragma unroll
  for (int nt = 0; nt < 8; nt++) acc[nt] = (f32x4){0.f, 0.f, 0.f, 0.f};
#pragma unroll
  for (int kc = 0; kc < 8; kc++) {
    const ushort* src = (kc < 4) ? (Abf + (size_t)rA * 128 + kc * 32)
                                 : (Xbf + (size_t)rA * 128 + (kc - 4) * 32);
    short8 a = *(const short8*)(src + quad * 8);
    const ushort* wp = Wp + (size_t)(kc * 8) * 512 + lane * 8;
#pragma unroll
    for (int nt = 0; nt < 8; nt++) {
      short8 b = *(const short8*)(wp + nt * 512);
      acc[nt] = __builtin_amdgcn_mfma_f32_16x16x32_bf16(a, b, acc[nt], 0, 0, 0);
    }
  }
#pragma unroll
  for (int nt = 0; nt < 8; nt++) {
    float bv = bias[nt * 16 + m];
#pragma unroll
    for (int r = 0; r < 4; r++) {
      int row = row0 + quad * 4 + r;
      if (row < rows) {
        float v = acc[nt][r] + bv;
        if (RELU) v = fmaxf(v, 0.f);
        if (OUTBF) outB[(size_t)row * 128 + nt * 16 + m] = f2bf(v);
        else       outF[(size_t)row * 128 + nt * 16 + m] = v;
      }
    }
  }
}

// ---------------- decoder: gather z1 -> MFMA z2 -> pred (nontemporal output streams) -----

__global__ __launch_bounds__(256) void decoder_mfma_k(const float* __restrict__ Za,
                                                      const float* __restrict__ Zh,
                                                      const int* __restrict__ rowi,
                                                      const int* __restrict__ coli,
                                                      const ushort* __restrict__ Wp,
                                                      const float* __restrict__ b1,
                                                      const float* __restrict__ W2,
                                                      const float* __restrict__ b2,
                                                      float* __restrict__ pred,
                                                      float* __restrict__ z1o,
                                                      float* __restrict__ z2o) {
  __shared__ ushort z1bf[64 * 264];  // row stride 264 bf16 = 528 B
  __shared__ int ra[64], rc[64];
  const int t = threadIdx.x, w = t >> 6, lane = t & 63, quad = lane >> 4, m = lane & 15;
  const int rb = blockIdx.x * 64;
  if (t < 64) ra[t] = rowi[rb + t];
  else if (t < 128) rc[t - 64] = coli[rb + t - 64];
  __syncthreads();
#pragma unroll 4
  for (int rr = 0; rr < 16; rr++) {
    int row = w * 16 + rr;
    int a = ra[row], c = rc[row];
    float2 va = *(const float2*)(Za + (size_t)a * 128 + lane * 2);
    float2 vc = *(const float2*)(Zh + (size_t)c * 128 + lane * 2);
    float* zr = z1o + (size_t)(rb + row) * 256;
    __builtin_nontemporal_store(*(const double*)&va, (double*)(zr + lane * 2));
    __builtin_nontemporal_store(*(const double*)&vc, (double*)(zr + 128 + lane * 2));
    uint* lbase = (uint*)(z1bf + row * 264);
    lbase[lane] = pack2bf(va.x, va.y);
    lbase[64 + lane] = pack2bf(vc.x, vc.y);
  }
  __syncthreads();
  f32x4 acc[8];
#pragma unroll
  for (int nt = 0; nt < 8; nt++) acc[nt] = (f32x4){0.f, 0.f, 0.f, 0.f};
#pragma unroll
  for (int kc = 0; kc < 8; kc++) {
    short8 a = *(const short8*)(z1bf + (w * 16 + m) * 264 + kc * 32 + quad * 8);
    const ushort* wp = Wp + (size_t)(kc * 8) * 512 + lane * 8;
#pragma unroll
    for (int nt = 0; nt < 8; nt++) {
      short8 b = *(const short8*)(wp + nt * 512);
      acc[nt] = __builtin_amdgcn_mfma_f32_16x16x32_bf16(a, b, acc[nt], 0, 0, 0);
    }
  }
  float part[4] = {0.f, 0.f, 0.f, 0.f};
#pragma unroll
  for (int nt = 0; nt < 8; nt++) {
    float bv = b1[nt * 16 + m];
    float wv = W2[nt * 16 + m];
#pragma unroll
    for (int r = 0; r < 4; r++) {
      float v = fmaxf(acc[nt][r] + bv, 0.f);
      __builtin_nontemporal_store(v, z2o + (size_t)(rb + w * 16 + quad * 4 + r) * 128 + nt * 16 + m);
      part[r] += v * wv;
    }
  }
  const float bias2 = b2[0];
#pragma unroll
  for (int r = 0; r < 4; r++) {
    float s = part[r];
    s += __shfl_xor(s, 1); s += __shfl_xor(s, 2);
    s += __shfl_xor(s, 4); s += __shfl_xor(s, 8);
    if (m == 0) pred[rb + w * 16 + quad * 4 + r] = s + bias2;
  }
}

// ---------------- host ----------------

static inline char* carve(char*& p, size_t bytes) {
  char* r = p;
  p += (bytes + 255) & ~(size_t)255;
  return r;
}

extern "C" void kernel_launch(void* const* d_in, const int* in_sizes, int n_in,
                              void* d_out, int out_size, void* d_ws, size_t ws_size,
                              hipStream_t stream) {
  const float* x_author = (const float*)d_in[0];
  const float* x_hotel  = (const float*)d_in[1];
  const int* ei_ah_src  = (const int*)d_in[2];
  const int* ei_ah_dst  = (const int*)d_in[3];
  const int* ei_ha_src  = (const int*)d_in[4];
  const int* ei_ha_dst  = (const int*)d_in[5];
  const int* eli_row    = (const int*)d_in[6];
  const int* eli_col    = (const int*)d_in[7];
  const float* W1_ah_l  = (const float*)d_in[8];
  const float* W1_ah_r  = (const float*)d_in[9];
  const float* W1_ha_l  = (const float*)d_in[10];
  const float* W1_ha_r  = (const float*)d_in[11];
  const float* W2_ah_l  = (const float*)d_in[12];
  const float* W2_ah_r  = (const float*)d_in[13];
  const float* W2_ha_l  = (const float*)d_in[14];
  const float* W2_ha_r  = (const float*)d_in[15];
  const float* b1_ah_l  = (const float*)d_in[16];
  const float* b1_ha_l  = (const float*)d_in[17];
  const float* b2_ah_l  = (const float*)d_in[18];
  const float* b2_ha_l  = (const float*)d_in[19];
  const float* W_lin1   = (const float*)d_in[20];
  const float* b_lin1   = (const float*)d_in[21];
  const float* W_lin2   = (const float*)d_in[22];
  const float* b_lin2   = (const float*)d_in[23];

  char* p = (char*)d_ws;
  ushort* xa_bf = (ushort*)carve(p, (size_t)NA_ * D_ * 2);
  ushort* xh_bf = (ushort*)carve(p, (size_t)NH_ * D_ * 2);
  ushort* A_hbf = (ushort*)carve(p, (size_t)NH_ * D_ * 2);
  ushort* A_abf = (ushort*)carve(p, (size_t)NA_ * D_ * 2);
  ushort* H_hbf = (ushort*)carve(p, (size_t)NH_ * D_ * 2);
  ushort* H_abf = (ushort*)carve(p, (size_t)NA_ * D_ * 2);
  float*  Z_h   = (float*)carve(p, (size_t)NH_ * D_ * 4);
  float*  Z_a   = (float*)carve(p, (size_t)NA_ * D_ * 4);
  ushort* Wp1ah = (ushort*)carve(p, 32768 * 2);
  ushort* Wp1ha = (ushort*)carve(p, 32768 * 2);
  ushort* Wp2ah = (ushort*)carve(p, 32768 * 2);
  ushort* Wp2ha = (ushort*)carve(p, 32768 * 2);
  ushort* WpD   = (ushort*)carve(p, 32768 * 2);
  int* off_h = (int*)carve(p, (size_t)(NH_ + 1) * 4);
  int* off_a = (int*)carve(p, (size_t)(NA_ + 1) * 4);
  int* cur_h = (int*)carve(p, (size_t)(NH_ + NA_) * 4);
  int* cur_a = cur_h + NH_;
  int* s_ah  = (int*)carve(p, (size_t)E_ * 4);
  int* s_ha  = (int*)carve(p, (size_t)E_ * 4);
  int* partials = (int*)carve(p, 256 * 4);

  float* pred = (float*)d_out;
  float* z1o  = pred + EL_;
  float* z2o  = z1o + (size_t)EL_ * 256;

  // --- counts + bf16 conversion (fused) ---
  hipMemsetAsync(cur_h, 0, (size_t)(NH_ + NA_) * 4, stream);
  cvt_count_k<<<(NA_ * 32 + NH_ * 32 + 255) / 256, 256, 0, stream>>>(
      x_author, xa_bf, x_hotel, xh_bf, ei_ah_dst, cur_h, ei_ha_dst, cur_a);

  // --- hierarchical scan: counts -> off (+ cur reseed) ---
  csr_partial_k<<<NBT_, 256, 0, stream>>>(cur_h, cur_a, partials);
  csr_scanp_k<<<1, 128, 0, stream>>>(partials, off_h, off_a);
  csr_scatter_k<<<NBT_, 256, 0, stream>>>(cur_h, off_h, cur_a, off_a, partials);

  fill_edges_k<<<(2 * E_ + 255) / 256, 256, 0, stream>>>(ei_ah_src, ei_ah_dst, cur_h, s_ah,
                                                         ei_ha_src, ei_ha_dst, cur_a, s_ha);

  // --- weight packing ---
  dim3 pg(128, 5);
  pack_all_k<<<pg, 256, 0, stream>>>(W1_ah_l, W1_ah_r, Wp1ah,
                                     W1_ha_l, W1_ha_r, Wp1ha,
                                     W2_ah_l, W2_ah_r, Wp2ah,
                                     W2_ha_l, W2_ha_r, Wp2ha,
                                     W_lin1, W_lin1 + 128 * 128, WpD);

  // --- layer 1 ---
  aggregate_bf_k<<<(NH_ + 3) / 4, 256, 0, stream>>>(xa_bf, off_h, s_ah, A_hbf, NH_);
  sage_mfma_k<true, true><<<(NH_ + 63) / 64, 256, 0, stream>>>(A_hbf, xh_bf, Wp1ah, b1_ah_l, nullptr, H_hbf, NH_);
  aggregate_bf_k<<<(NA_ + 3) / 4, 256, 0, stream>>>(xh_bf, off_a, s_ha, A_abf, NA_);
  sage_mfma_k<true, true><<<(NA_ + 63) / 64, 256, 0, stream>>>(A_abf, xa_bf, Wp1ha, b1_ha_l, nullptr, H_abf, NA_);

  // --- layer 2 (fp32 outputs) ---
  aggregate_bf_k<<<(NH_ + 3) / 4, 256, 0, stream>>>(H_abf, off_h, s_ah, A_hbf, NH_);
  sage_mfma_k<false, false><<<(NH_ + 63) / 64, 256, 0, stream>>>(A_hbf, H_hbf, Wp2ah, b2_ah_l, Z_h, nullptr, NH_);
  aggregate_bf_k<<<(NA_ + 3) / 4, 256, 0, stream>>>(H_hbf, off_a, s_ha, A_abf, NA_);
  sage_mfma_k<false, false><<<(NA_ + 63) / 64, 256, 0, stream>>>(A_abf, H_abf, Wp2ha, b2_ha_l, Z_a, nullptr, NA_);

  // --- decoder ---
  decoder_mfma_k<<<EL_ / 64, 256, 0, stream>>>(Z_a, Z_h, eli_row, eli_col,
                                               WpD, b_lin1, W_lin2, b_lin2,
                                               pred, z1o, z2o);
}

// Round 3
// 890.133 us; speedup vs baseline: 1.3513x; 1.0166x over previous
//
#include <hip/hip_runtime.h>

#define NA_ 100000
#define NH_ 20000
#define E_  1000000
#define EL_ 200000
#define D_  128

// hierarchical scan geometry: 1024 elements per chunk
#define NBH_ 20    // ceil(NH/1024)
#define NBA_ 98    // ceil(NA/1024)
#define NBT_ 118   // NBH_ + NBA_

// fused sage geometry: 64 rows per block
#define FBH_ 313   // ceil(NH/64)
#define FBA_ 1563  // ceil(NA/64)

typedef __attribute__((ext_vector_type(8))) short short8;
typedef __attribute__((ext_vector_type(4))) float f32x4;

__device__ __forceinline__ ushort f2bf(float f) {
  union { float f; uint u; } v; v.f = f;
  uint u = v.u;
  return (ushort)((u + 0x7FFFu + ((u >> 16) & 1u)) >> 16);
}
__device__ __forceinline__ uint pack2bf(float a, float b) {
  return (uint)f2bf(a) | ((uint)f2bf(b) << 16);
}

// ---------------- fused fp32->bf16 conversion + edge counting ----------------

__global__ __launch_bounds__(256) void cvt_count_k(const float* __restrict__ xa, ushort* __restrict__ da,
                                                   const float* __restrict__ xh, ushort* __restrict__ dh,
                                                   const int* __restrict__ d1, int* __restrict__ c1,
                                                   const int* __restrict__ d2, int* __restrict__ c2) {
  int i = blockIdx.x * 256 + threadIdx.x;
  if (i < E_) atomicAdd(&c1[d1[i]], 1);
  else if (i < 2 * E_) atomicAdd(&c2[d2[i - E_]], 1);
  const int na4 = NA_ * 32;
  if (i < na4) {
    float4 v = *(const float4*)(xa + (size_t)i * 4);
    ((uint2*)da)[i] = make_uint2(pack2bf(v.x, v.y), pack2bf(v.z, v.w));
  } else {
    int k = i - na4;
    if (k < NH_ * 32) {
      float4 v = *(const float4*)(xh + (size_t)k * 4);
      ((uint2*)dh)[k] = make_uint2(pack2bf(v.x, v.y), pack2bf(v.z, v.w));
    }
  }
}

// ---------------- hierarchical CSR prefix scan ----------------

__global__ __launch_bounds__(256) void csr_partial_k(const int* __restrict__ cnt_h,
                                                     const int* __restrict__ cnt_a,
                                                     int* __restrict__ partials) {
  int b = blockIdx.x;
  bool isH = b < NBH_;
  const int* c = isH ? cnt_h : cnt_a;
  int n = isH ? NH_ : NA_;
  int chunk = isH ? b : b - NBH_;
  int t = threadIdx.x;
  int i0 = chunk * 1024 + t * 4;
  int s = 0;
  if (i0 + 3 < n) {
    int4 v = *(const int4*)(c + i0);
    s = v.x + v.y + v.z + v.w;
  } else {
    for (int k = 0; k < 4; k++) if (i0 + k < n) s += c[i0 + k];
  }
#pragma unroll
  for (int d = 1; d < 64; d <<= 1) s += __shfl_xor(s, d);
  __shared__ int ws[4];
  int lane = t & 63, wv = t >> 6;
  if (lane == 0) ws[wv] = s;
  __syncthreads();
  if (t == 0) partials[b] = ws[0] + ws[1] + ws[2] + ws[3];
}

__global__ __launch_bounds__(128) void csr_scanp_k(int* __restrict__ partials,
                                                   int* __restrict__ off_h,
                                                   int* __restrict__ off_a) {
  __shared__ int s[128];
  int t = threadIdx.x;
  int orig = (t < NBT_) ? partials[t] : 0;
  int seg = (t < NBH_) ? 0 : 1;
  s[t] = orig;
  __syncthreads();
  for (int d = 1; d < 128; d <<= 1) {
    int v = 0;
    if (t >= d) {
      int o = t - d;
      if (((o < NBH_) ? 0 : 1) == seg) v = s[o];
    }
    __syncthreads();
    s[t] += v;
    __syncthreads();
  }
  if (t < NBT_) partials[t] = s[t] - orig;  // exclusive base per chunk
  if (t == 0) { off_h[NH_] = E_; off_a[NA_] = E_; }
}

__global__ __launch_bounds__(256) void csr_scatter_k(int* __restrict__ cnt_h, int* __restrict__ off_h,
                                                     int* __restrict__ cnt_a, int* __restrict__ off_a,
                                                     const int* __restrict__ partials) {
  int b = blockIdx.x;
  bool isH = b < NBH_;
  int* c = isH ? cnt_h : cnt_a;     // counts in, cur out (aliased buffer)
  int* off = isH ? off_h : off_a;
  int n = isH ? NH_ : NA_;
  int chunk = isH ? b : b - NBH_;
  int t = threadIdx.x, lane = t & 63, wv = t >> 6;
  int base = partials[b];
  int i0 = chunk * 1024 + t * 4;
  int v0 = 0, v1 = 0, v2 = 0, v3 = 0;
  if (i0 + 3 < n) {
    int4 v = *(const int4*)(c + i0);
    v0 = v.x; v1 = v.y; v2 = v.z; v3 = v.w;
  } else {
    if (i0 < n) v0 = c[i0];
    if (i0 + 1 < n) v1 = c[i0 + 1];
    if (i0 + 2 < n) v2 = c[i0 + 2];
    if (i0 + 3 < n) v3 = c[i0 + 3];
  }
  int tsum = v0 + v1 + v2 + v3;
  int x = tsum;
#pragma unroll
  for (int d = 1; d < 64; d <<= 1) { int y = __shfl_up(x, d); if (lane >= d) x += y; }
  __shared__ int ws[4], wb[4];
  if (lane == 63) ws[wv] = x;
  __syncthreads();
  if (t == 0) { int r = 0; for (int i = 0; i < 4; i++) { wb[i] = r; r += ws[i]; } }
  __syncthreads();
  int run = base + wb[wv] + (x - tsum);
  int o0 = run, o1 = o0 + v0, o2 = o1 + v1, o3 = o2 + v2;
  if (i0 + 3 < n) {
    *(int4*)(off + i0) = make_int4(o0, o1, o2, o3);
    *(int4*)(c + i0) = make_int4(o0, o1, o2, o3);
  } else {
    if (i0 < n) { off[i0] = o0; c[i0] = o0; }
    if (i0 + 1 < n) { off[i0 + 1] = o1; c[i0 + 1] = o1; }
    if (i0 + 2 < n) { off[i0 + 2] = o2; c[i0 + 2] = o2; }
    if (i0 + 3 < n) { off[i0 + 3] = o3; c[i0 + 3] = o3; }
  }
}

__global__ void fill_edges_k(const int* __restrict__ s1, const int* __restrict__ d1,
                             int* __restrict__ cur1, int* __restrict__ out1,
                             const int* __restrict__ s2, const int* __restrict__ d2,
                             int* __restrict__ cur2, int* __restrict__ out2) {
  int i = blockIdx.x * 256 + threadIdx.x;
  if (i < E_) {
    int p = atomicAdd(&cur1[d1[i]], 1);
    out1[p] = s1[i];
  } else if (i < 2 * E_) {
    int ii = i - E_;
    int p = atomicAdd(&cur2[d2[ii]], 1);
    out2[p] = s2[ii];
  }
}

// ---------------- pack [Wl;Wr] (K=256, N=128) into MFMA B-frag layout, bf16 ----------------

__global__ void pack_all_k(const float* a0, const float* a1, ushort* ad,
                           const float* b0, const float* b1, ushort* bd,
                           const float* c0, const float* c1, ushort* cd,
                           const float* d0, const float* d1, ushort* dd,
                           const float* e0, const float* e1, ushort* ed) {
  const float *s0, *s1; ushort* dst;
  switch (blockIdx.y) {
    case 0: s0 = a0; s1 = a1; dst = ad; break;
    case 1: s0 = b0; s1 = b1; dst = bd; break;
    case 2: s0 = c0; s1 = c1; dst = cd; break;
    case 3: s0 = d0; s1 = d1; dst = dd; break;
    default: s0 = e0; s1 = e1; dst = ed; break;
  }
  int idx = blockIdx.x * 256 + threadIdx.x;  // 0..32767
  int j = idx & 7, lane = (idx >> 3) & 63, nt = (idx >> 9) & 7, kc = idx >> 12;
  int k = kc * 32 + (lane >> 4) * 8 + j;
  int n = nt * 16 + (lane & 15);
  float v = (k < 128) ? s0[k * 128 + n] : s1[(k - 128) * 128 + n];
  dst[idx] = f2bf(v);
}

// ---------------- fused SAGE: mean-aggregate (to LDS) + MFMA transform ----------------
// block = 256 thr = 4 waves, 64 rows/block (16 rows/wave).
// Two node-type parts in one grid: blocks [0,nb0) = part0, rest = part1.
// out = act([mean_agg | X] @ Wp + bias)

template <bool RELU, bool OUTBF>
__global__ __launch_bounds__(256) void sage_fused_k(
    const int* __restrict__ off0, const int* __restrict__ src0,
    const ushort* __restrict__ G0, const ushort* __restrict__ X0,
    const ushort* __restrict__ W0, const float* __restrict__ B0,
    ushort* __restrict__ oB0, float* __restrict__ oF0, int n0, int nb0,
    const int* __restrict__ off1, const int* __restrict__ src1,
    const ushort* __restrict__ G1, const ushort* __restrict__ X1,
    const ushort* __restrict__ W1, const float* __restrict__ B1,
    ushort* __restrict__ oB1, float* __restrict__ oF1, int n1) {
  const int b = blockIdx.x;
  const bool p0 = b < nb0;
  const int* off = p0 ? off0 : off1;
  const int* srcs = p0 ? src0 : src1;
  const ushort* G = p0 ? G0 : G1;
  const ushort* X = p0 ? X0 : X1;
  const ushort* Wp = p0 ? W0 : W1;
  const float* bias = p0 ? B0 : B1;
  ushort* outB = p0 ? oB0 : oB1;
  float* outF = p0 ? oF0 : oF1;
  const int rows = p0 ? n0 : n1;
  const int rb = (p0 ? b : b - nb0) * 64;

  __shared__ ushort At[64 * 136];  // row stride 272 B (16B-aligned)

  const int t = threadIdx.x, w = t >> 6, lane = t & 63;
  const int grp = lane >> 4, sub = lane & 15;
  const ushort* gbase = G + sub * 8;

  // --- aggregate 16 rows per wave into LDS ---
  for (int rr = 0; rr < 16; rr++) {
    int row = rb + w * 16 + rr;
    float a[8] = {0.f, 0.f, 0.f, 0.f, 0.f, 0.f, 0.f, 0.f};
    int deg = 0;
    if (row < rows) {
      int beg = off[row], end = off[row + 1];
      deg = end - beg;
      int j = beg + grp;
      for (; j + 4 < end; j += 8) {
        int sA = srcs[j];
        int sB = srcs[j + 4];
        uint4 vA = *(const uint4*)(gbase + (size_t)sA * 128);
        uint4 vB = *(const uint4*)(gbase + (size_t)sB * 128);
        a[0] += __uint_as_float(vA.x << 16); a[1] += __uint_as_float(vA.x & 0xFFFF0000u);
        a[2] += __uint_as_float(vA.y << 16); a[3] += __uint_as_float(vA.y & 0xFFFF0000u);
        a[4] += __uint_as_float(vA.z << 16); a[5] += __uint_as_float(vA.z & 0xFFFF0000u);
        a[6] += __uint_as_float(vA.w << 16); a[7] += __uint_as_float(vA.w & 0xFFFF0000u);
        a[0] += __uint_as_float(vB.x << 16); a[1] += __uint_as_float(vB.x & 0xFFFF0000u);
        a[2] += __uint_as_float(vB.y << 16); a[3] += __uint_as_float(vB.y & 0xFFFF0000u);
        a[4] += __uint_as_float(vB.z << 16); a[5] += __uint_as_float(vB.z & 0xFFFF0000u);
        a[6] += __uint_as_float(vB.w << 16); a[7] += __uint_as_float(vB.w & 0xFFFF0000u);
      }
      if (j < end) {
        int sA = srcs[j];
        uint4 vA = *(const uint4*)(gbase + (size_t)sA * 128);
        a[0] += __uint_as_float(vA.x << 16); a[1] += __uint_as_float(vA.x & 0xFFFF0000u);
        a[2] += __uint_as_float(vA.y << 16); a[3] += __uint_as_float(vA.y & 0xFFFF0000u);
        a[4] += __uint_as_float(vA.z << 16); a[5] += __uint_as_float(vA.z & 0xFFFF0000u);
        a[6] += __uint_as_float(vA.w << 16); a[7] += __uint_as_float(vA.w & 0xFFFF0000u);
      }
#pragma unroll
      for (int k = 0; k < 8; k++) {
        a[k] += __shfl_xor(a[k], 16);
        a[k] += __shfl_xor(a[k], 32);
      }
    }
    if (grp == 0) {
      float sc = 1.0f / (float)(deg > 0 ? deg : 1);
      uint4 o;
      o.x = pack2bf(a[0] * sc, a[1] * sc);
      o.y = pack2bf(a[2] * sc, a[3] * sc);
      o.z = pack2bf(a[4] * sc, a[5] * sc);
      o.w = pack2bf(a[6] * sc, a[7] * sc);
      *(uint4*)(At + (w * 16 + rr) * 136 + sub * 8) = o;
    }
  }
  __syncthreads();

  // --- MFMA transform ---
  const int quad = lane >> 4, m = lane & 15;
  int rA = rb + w * 16 + m; if (rA >= rows) rA = rows - 1;
  f32x4 acc[8];
#pragma unroll
  for (int nt = 0; nt < 8; nt++) acc[nt] = (f32x4){0.f, 0.f, 0.f, 0.f};
#pragma unroll
  for (int kc = 0; kc < 8; kc++) {
    short8 a;
    if (kc < 4) a = *(const short8*)(At + (w * 16 + m) * 136 + kc * 32 + quad * 8);
    else        a = *(const short8*)(X + (size_t)rA * 128 + (kc - 4) * 32 + quad * 8);
    const ushort* wp = Wp + (size_t)(kc * 8) * 512 + lane * 8;
#pragma unroll
    for (int nt = 0; nt < 8; nt++) {
      short8 bfr = *(const short8*)(wp + nt * 512);
      acc[nt] = __builtin_amdgcn_mfma_f32_16x16x32_bf16(a, bfr, acc[nt], 0, 0, 0);
    }
  }
#pragma unroll
  for (int nt = 0; nt < 8; nt++) {
    float bv = bias[nt * 16 + m];
#pragma unroll
    for (int r = 0; r < 4; r++) {
      int row = rb + w * 16 + quad * 4 + r;
      if (row < rows) {
        float v = acc[nt][r] + bv;
        if (RELU) v = fmaxf(v, 0.f);
        if (OUTBF) outB[(size_t)row * 128 + nt * 16 + m] = f2bf(v);
        else       outF[(size_t)row * 128 + nt * 16 + m] = v;
      }
    }
  }
}

// ---------------- decoder: gather z1 -> MFMA z2 -> pred (nontemporal output streams) -----

__global__ __launch_bounds__(256) void decoder_mfma_k(const float* __restrict__ Za,
                                                      const float* __restrict__ Zh,
                                                      const int* __restrict__ rowi,
                                                      const int* __restrict__ coli,
                                                      const ushort* __restrict__ Wp,
                                                      const float* __restrict__ b1,
                                                      const float* __restrict__ W2,
                                                      const float* __restrict__ b2,
                                                      float* __restrict__ pred,
                                                      float* __restrict__ z1o,
                                                      float* __restrict__ z2o) {
  __shared__ ushort z1bf[64 * 264];  // row stride 264 bf16 = 528 B
  __shared__ int ra[64], rc[64];
  const int t = threadIdx.x, w = t >> 6, lane = t & 63, quad = lane >> 4, m = lane & 15;
  const int rb = blockIdx.x * 64;
  if (t < 64) ra[t] = rowi[rb + t];
  else if (t < 128) rc[t - 64] = coli[rb + t - 64];
  __syncthreads();
#pragma unroll 4
  for (int rr = 0; rr < 16; rr++) {
    int row = w * 16 + rr;
    int a = ra[row], c = rc[row];
    float2 va = *(const float2*)(Za + (size_t)a * 128 + lane * 2);
    float2 vc = *(const float2*)(Zh + (size_t)c * 128 + lane * 2);
    float* zr = z1o + (size_t)(rb + row) * 256;
    __builtin_nontemporal_store(*(const double*)&va, (double*)(zr + lane * 2));
    __builtin_nontemporal_store(*(const double*)&vc, (double*)(zr + 128 + lane * 2));
    uint* lbase = (uint*)(z1bf + row * 264);
    lbase[lane] = pack2bf(va.x, va.y);
    lbase[64 + lane] = pack2bf(vc.x, vc.y);
  }
  __syncthreads();
  f32x4 acc[8];
#pragma unroll
  for (int nt = 0; nt < 8; nt++) acc[nt] = (f32x4){0.f, 0.f, 0.f, 0.f};
#pragma unroll
  for (int kc = 0; kc < 8; kc++) {
    short8 a = *(const short8*)(z1bf + (w * 16 + m) * 264 + kc * 32 + quad * 8);
    const ushort* wp = Wp + (size_t)(kc * 8) * 512 + lane * 8;
#pragma unroll
    for (int nt = 0; nt < 8; nt++) {
      short8 b = *(const short8*)(wp + nt * 512);
      acc[nt] = __builtin_amdgcn_mfma_f32_16x16x32_bf16(a, b, acc[nt], 0, 0, 0);
    }
  }
  float part[4] = {0.f, 0.f, 0.f, 0.f};
#pragma unroll
  for (int nt = 0; nt < 8; nt++) {
    float bv = b1[nt * 16 + m];
    float wv = W2[nt * 16 + m];
#pragma unroll
    for (int r = 0; r < 4; r++) {
      float v = fmaxf(acc[nt][r] + bv, 0.f);
      __builtin_nontemporal_store(v, z2o + (size_t)(rb + w * 16 + quad * 4 + r) * 128 + nt * 16 + m);
      part[r] += v * wv;
    }
  }
  const float bias2 = b2[0];
#pragma unroll
  for (int r = 0; r < 4; r++) {
    float s = part[r];
    s += __shfl_xor(s, 1); s += __shfl_xor(s, 2);
    s += __shfl_xor(s, 4); s += __shfl_xor(s, 8);
    if (m == 0) pred[rb + w * 16 + quad * 4 + r] = s + bias2;
  }
}

// ---------------- host ----------------

static inline char* carve(char*& p, size_t bytes) {
  char* r = p;
  p += (bytes + 255) & ~(size_t)255;
  return r;
}

extern "C" void kernel_launch(void* const* d_in, const int* in_sizes, int n_in,
                              void* d_out, int out_size, void* d_ws, size_t ws_size,
                              hipStream_t stream) {
  const float* x_author = (const float*)d_in[0];
  const float* x_hotel  = (const float*)d_in[1];
  const int* ei_ah_src  = (const int*)d_in[2];
  const int* ei_ah_dst  = (const int*)d_in[3];
  const int* ei_ha_src  = (const int*)d_in[4];
  const int* ei_ha_dst  = (const int*)d_in[5];
  const int* eli_row    = (const int*)d_in[6];
  const int* eli_col    = (const int*)d_in[7];
  const float* W1_ah_l  = (const float*)d_in[8];
  const float* W1_ah_r  = (const float*)d_in[9];
  const float* W1_ha_l  = (const float*)d_in[10];
  const float* W1_ha_r  = (const float*)d_in[11];
  const float* W2_ah_l  = (const float*)d_in[12];
  const float* W2_ah_r  = (const float*)d_in[13];
  const float* W2_ha_l  = (const float*)d_in[14];
  const float* W2_ha_r  = (const float*)d_in[15];
  const float* b1_ah_l  = (const float*)d_in[16];
  const float* b1_ha_l  = (const float*)d_in[17];
  const float* b2_ah_l  = (const float*)d_in[18];
  const float* b2_ha_l  = (const float*)d_in[19];
  const float* W_lin1   = (const float*)d_in[20];
  const float* b_lin1   = (const float*)d_in[21];
  const float* W_lin2   = (const float*)d_in[22];
  const float* b_lin2   = (const float*)d_in[23];

  char* p = (char*)d_ws;
  ushort* xa_bf = (ushort*)carve(p, (size_t)NA_ * D_ * 2);
  ushort* xh_bf = (ushort*)carve(p, (size_t)NH_ * D_ * 2);
  ushort* H_hbf = (ushort*)carve(p, (size_t)NH_ * D_ * 2);
  ushort* H_abf = (ushort*)carve(p, (size_t)NA_ * D_ * 2);
  float*  Z_h   = (float*)carve(p, (size_t)NH_ * D_ * 4);
  float*  Z_a   = (float*)carve(p, (size_t)NA_ * D_ * 4);
  ushort* Wp1ah = (ushort*)carve(p, 32768 * 2);
  ushort* Wp1ha = (ushort*)carve(p, 32768 * 2);
  ushort* Wp2ah = (ushort*)carve(p, 32768 * 2);
  ushort* Wp2ha = (ushort*)carve(p, 32768 * 2);
  ushort* WpD   = (ushort*)carve(p, 32768 * 2);
  int* off_h = (int*)carve(p, (size_t)(NH_ + 1) * 4);
  int* off_a = (int*)carve(p, (size_t)(NA_ + 1) * 4);
  int* cur_h = (int*)carve(p, (size_t)(NH_ + NA_) * 4);
  int* cur_a = cur_h + NH_;
  int* s_ah  = (int*)carve(p, (size_t)E_ * 4);
  int* s_ha  = (int*)carve(p, (size_t)E_ * 4);
  int* partials = (int*)carve(p, 256 * 4);

  float* pred = (float*)d_out;
  float* z1o  = pred + EL_;
  float* z2o  = z1o + (size_t)EL_ * 256;

  // --- counts + bf16 conversion (fused) ---
  hipMemsetAsync(cur_h, 0, (size_t)(NH_ + NA_) * 4, stream);
  cvt_count_k<<<(NA_ * 32 + NH_ * 32 + 255) / 256, 256, 0, stream>>>(
      x_author, xa_bf, x_hotel, xh_bf, ei_ah_dst, cur_h, ei_ha_dst, cur_a);

  // --- hierarchical scan: counts -> off (+ cur reseed) ---
  csr_partial_k<<<NBT_, 256, 0, stream>>>(cur_h, cur_a, partials);
  csr_scanp_k<<<1, 128, 0, stream>>>(partials, off_h, off_a);
  csr_scatter_k<<<NBT_, 256, 0, stream>>>(cur_h, off_h, cur_a, off_a, partials);

  fill_edges_k<<<(2 * E_ + 255) / 256, 256, 0, stream>>>(ei_ah_src, ei_ah_dst, cur_h, s_ah,
                                                         ei_ha_src, ei_ha_dst, cur_a, s_ha);

  // --- weight packing ---
  dim3 pg(128, 5);
  pack_all_k<<<pg, 256, 0, stream>>>(W1_ah_l, W1_ah_r, Wp1ah,
                                     W1_ha_l, W1_ha_r, Wp1ha,
                                     W2_ah_l, W2_ah_r, Wp2ah,
                                     W2_ha_l, W2_ha_r, Wp2ha,
                                     W_lin1, W_lin1 + 128 * 128, WpD);

  // --- layer 1: both node types, one launch (agg + transform fused) ---
  sage_fused_k<true, true><<<FBH_ + FBA_, 256, 0, stream>>>(
      off_h, s_ah, xa_bf, xh_bf, Wp1ah, b1_ah_l, H_hbf, nullptr, NH_, FBH_,
      off_a, s_ha, xh_bf, xa_bf, Wp1ha, b1_ha_l, H_abf, nullptr, NA_);

  // --- layer 2: both node types, one launch (fp32 outputs) ---
  sage_fused_k<false, false><<<FBH_ + FBA_, 256, 0, stream>>>(
      off_h, s_ah, H_abf, H_hbf, Wp2ah, b2_ah_l, nullptr, Z_h, NH_, FBH_,
      off_a, s_ha, H_hbf, H_abf, Wp2ha, b2_ha_l, nullptr, Z_a, NA_);

  // --- decoder ---
  decoder_mfma_k<<<EL_ / 64, 256, 0, stream>>>(Z_a, Z_h, eli_row, eli_col,
                                               WpD, b_lin1, W_lin2, b_lin2,
                                               pred, z1o, z2o);
}